// Round 1
// baseline (325.365 us; speedup 1.0000x reference)
//
#include <hip/hip_runtime.h>
#include <hip/hip_bf16.h>

// Problem constants (BayesianLinear): IN_F=64, OUT_F=32, N=2080, B*S=16384
#define IN_F  64
#define OUT_F 32
#define NV    2080           // N
#define NPAD  2176           // 17*128
#define MM    16384          // tokens
#define KK    2080           // contraction dim
#define NBN   17             // column tiles
#define BM    256            // V2 row-tile

#define CVT_BLKS 16640       // MM*KK/(256*8)
#define L_BLKS   17680       // NPAD*KK/256

typedef __attribute__((ext_vector_type(4))) float f32x4;
typedef __bf16 bf16x8 __attribute__((ext_vector_type(8)));

using gas_ptr = const __attribute__((address_space(1))) void*;
using lds_ptr = __attribute__((address_space(3))) void*;

// ---------------------------------------------------------------------------
// Kernel 1 (new path): fused prep — eps fp32 -> bf16 copy, and build L (bf16).
// Grid split by blockIdx: [0,CVT_BLKS) converts eps, rest builds L.
// ---------------------------------------------------------------------------
__global__ __launch_bounds__(256) void prep_k(const float* __restrict__ eps,
                                              const float* __restrict__ cov,
                                              const float* __restrict__ logvar,
                                              __hip_bfloat16* __restrict__ EB,
                                              __hip_bfloat16* __restrict__ LB) {
    const int b = blockIdx.x;
    if (b < CVT_BLKS) {
        const size_t i = ((size_t)b * 256 + threadIdx.x) * 8;
        const f32x4 a0 = *(const f32x4*)(eps + i);
        const f32x4 a1 = *(const f32x4*)(eps + i + 4);
        bf16x8 w;
#pragma unroll
        for (int q = 0; q < 4; q++) { w[q] = (__bf16)a0[q]; w[4 + q] = (__bf16)a1[q]; }
        *(bf16x8*)(EB + i) = w;
    } else {
        const int idx = (b - CVT_BLKS) * 256 + threadIdx.x;   // over NPAD*KK
        const int m = idx / KK;
        const int k = idx - m * KK;
        float v = 0.0f;
        if (m < NV) {
            if (k < m)       v = cov[(size_t)(m * (m - 1) / 2) + k];
            else if (k == m) v = expf(0.5f * logvar[m]);
        }
        LB[idx] = __float2bfloat16(v);
    }
}

// ---------------------------------------------------------------------------
// Kernel 1 (fallback path): build L only (verified R-prev code, unchanged).
// ---------------------------------------------------------------------------
__global__ __launch_bounds__(256) void build_L_k(const float* __restrict__ cov,
                                                 const float* __restrict__ logvar,
                                                 __hip_bfloat16* __restrict__ LB) {
    const int idx = blockIdx.x * 256 + threadIdx.x;   // over NPAD*KK
    const int m = idx / KK;
    const int k = idx - m * KK;
    float v = 0.0f;
    if (m < NV) {
        if (k < m)       v = cov[(size_t)(m * (m - 1) / 2) + k];
        else if (k == m) v = expf(0.5f * logvar[m]);
    }
    LB[idx] = __float2bfloat16(v);
}

// ---------------------------------------------------------------------------
// Kernel 2 (new): BM=256 x 128 tile, both operands bf16 via global_load_lds
// with pre-swizzled source offsets (slot(row,p) holds part p^((row>>1)&3)).
// Triple-buffered distance-2 prefetch with counted vmcnt(6) + raw s_barrier:
// loads for t+1,t+2 stay in flight across every barrier (never drain in the
// main loop).  4 waves x acc[4][8] (64x128 per wave) -> 0.375 ds_read_b128
// per MFMA.  Exact triangular frag-skip: jlo = max(0, 2*kb - 8*bn); hot loop
// (jlo==0) kept branchless by splitting the last <=3 iterations.
// In-lane x-contraction epilogue identical to the verified R-prev kernel.
// ---------------------------------------------------------------------------
__global__ __launch_bounds__(256, 2) void gemm_v2_k(const __hip_bfloat16* __restrict__ EB,
                                                    const __hip_bfloat16* __restrict__ LBt,
                                                    const float* __restrict__ loc,
                                                    const float* __restrict__ x,
                                                    float* __restrict__ Ypart) {
    __shared__ __align__(16) __hip_bfloat16 As[3][BM * 32];    // 48 KB
    __shared__ __align__(16) __hip_bfloat16 Bs[3][128 * 32];   // 24 KB
    __shared__ float xs[BM][4];                                //  4 KB

    const int tid  = threadIdx.x;
    const int bm   = blockIdx.x;             // 0..63
    const int bn   = (NBN - 1) - blockIdx.y; // heaviest (bn=16) first
    const int wave = tid >> 6;
    const int lane = tid & 63;
    const int quad = lane >> 4;
    const int r16  = lane & 15;
    const int kblocks = min(KK / 32, 4 * bn + 4);

    // xs: weight for h = 4bn-1+c; bias (1.0) at bn==0,c==0.  One row/thread
    // -> wave-local (rows 64w..64w+63 written by the same wave that reads them).
    {
        const int row = bm * BM + tid;
#pragma unroll
        for (int c = 0; c < 4; c++) {
            const int h = 4 * bn - 1 + c;
            float w = 0.0f;
            if (bn == 0 && c == 0)       w = 1.0f;
            else if (h >= 0 && h < IN_F) w = x[(size_t)row * IN_F + h];
            xs[tid][c] = w;
        }
    }

    const __hip_bfloat16* __restrict__ Ag = EB  + (size_t)bm * BM * KK;
    const __hip_bfloat16* __restrict__ Bg = LBt + (size_t)bn * 128 * KK;

    // staging chunk mapping: chunk c -> slot (c>>2, c&3) holding global part
    // (c&3)^((row>>1)&3); A: 1024 chunks (4/thread), B: 512 chunks (2/thread)
    size_t agofs[4]; int aldso[4];
#pragma unroll
    for (int u = 0; u < 4; u++) {
        const int c = tid + 256 * u;
        const int r = c >> 2, p = (c & 3) ^ ((r >> 1) & 3);
        agofs[u] = (size_t)r * KK + (size_t)(p * 8);
        aldso[u] = c * 8;
    }
    size_t bgofs[2]; int bldso[2];
#pragma unroll
    for (int u = 0; u < 2; u++) {
        const int c = tid + 256 * u;
        const int r = c >> 2, p = (c & 3) ^ ((r >> 1) & 3);
        bgofs[u] = (size_t)r * KK + (size_t)(p * 8);
        bldso[u] = c * 8;
    }

    // fragment-read LDS offsets (elements), same verified swizzle
    int aofs[4], bofs[8];
#pragma unroll
    for (int i = 0; i < 4; i++) {
        const int arow = 64 * wave + 16 * i + r16;
        aofs[i] = arow * 32 + (quad ^ ((arow >> 1) & 3)) * 8;
    }
#pragma unroll
    for (int j = 0; j < 8; j++) {
        const int brow = 16 * j + r16;
        bofs[j] = brow * 32 + (quad ^ ((brow >> 1) & 3)) * 8;
    }

    f32x4 acc[4][8];
#pragma unroll
    for (int i = 0; i < 4; i++)
#pragma unroll
        for (int j = 0; j < 8; j++) acc[i][j] = f32x4{0.f, 0.f, 0.f, 0.f};

    auto stage = [&](int t, int buf) __attribute__((always_inline)) {
        const size_t k0 = (size_t)t * 32;
#pragma unroll
        for (int u = 0; u < 4; u++)
            __builtin_amdgcn_global_load_lds((gas_ptr)(Ag + k0 + agofs[u]),
                                             (lds_ptr)(&As[buf][0] + aldso[u]), 16, 0, 0);
#pragma unroll
        for (int u = 0; u < 2; u++)
            __builtin_amdgcn_global_load_lds((gas_ptr)(Bg + k0 + bgofs[u]),
                                             (lds_ptr)(&Bs[buf][0] + bldso[u]), 16, 0, 0);
    };

    // prologue: tiles 0 and 1 in flight; wait tile 0 only (vmcnt 6 = tile 1)
    stage(0, 0);
    stage(1, 1);
    asm volatile("s_waitcnt lgkmcnt(0)" ::: "memory");   // xs committed
    asm volatile("s_waitcnt vmcnt(6)" ::: "memory");     // tile 0 landed
    __builtin_amdgcn_s_barrier();
    __builtin_amdgcn_sched_barrier(0);

    // per-iteration body.  Invariant at entry: buf[t%3] ready for ALL waves;
    // glds outstanding: tile t+1 (6) [+ tile t+2 (6) after stage below].
    auto iter = [&](int t, int jlo) __attribute__((always_inline)) {
        if (t + 2 < kblocks) stage(t + 2, (t + 2) % 3);  // overwrites buf of t-1 (reads done pre-barrier)
        const __hip_bfloat16* as = &As[t % 3][0];
        const __hip_bfloat16* bs = &Bs[t % 3][0];
        bf16x8 af[4], bfr[8];
#pragma unroll
        for (int i = 0; i < 4; i++) af[i] = *(const bf16x8*)(as + aofs[i]);
#pragma unroll
        for (int j = 0; j < 8; j++)
            if (j >= jlo) bfr[j] = *(const bf16x8*)(bs + bofs[j]);
#pragma unroll
        for (int j = 0; j < 8; j++)
            if (j >= jlo)
#pragma unroll
                for (int i = 0; i < 4; i++)
                    acc[i][j] = __builtin_amdgcn_mfma_f32_16x16x32_bf16(af[i], bfr[j], acc[i][j], 0, 0, 0);
        // end-of-iter: guarantee tile t+1 landed for this wave, then barrier.
        if (t + 2 < kblocks) {
            asm volatile("s_waitcnt vmcnt(6)" ::: "memory");  // keep t+2's 6 in flight
            __builtin_amdgcn_s_barrier();
            __builtin_amdgcn_sched_barrier(0);
        } else if (t + 1 < kblocks) {
            asm volatile("s_waitcnt vmcnt(0)" ::: "memory");  // nothing newer to keep
            __builtin_amdgcn_s_barrier();
            __builtin_amdgcn_sched_barrier(0);
        }
    };

    const int t_full = min(kblocks, 4 * bn + 1);   // jlo==0 region
    int t = 0;
    for (; t < t_full; ++t) iter(t, 0);
    for (; t < kblocks; ++t) iter(t, 2 * t - 8 * bn);   // jlo in {2,4,6}

    // in-lane epilogue.  C/D layout (m89): col=lane&15 (per 16-tile), row=quad*4+reg
    float locv[8];
#pragma unroll
    for (int j = 0; j < 8; j++) {
        const int col = bn * 128 + 16 * j + r16;
        locv[j] = (col < NV) ? loc[col] : 0.0f;
    }

    float* yp = Ypart + ((size_t)bn * MM + (size_t)bm * BM) * OUT_F;
#pragma unroll
    for (int i = 0; i < 4; i++) {
#pragma unroll
        for (int r = 0; r < 4; r++) {
            const int tl = 64 * wave + 16 * i + 4 * quad + r;
            float v0 = 0.0f, v1 = 0.0f;
#pragma unroll
            for (int c = 0; c < 4; c++) {
                const float w = xs[tl][c];
                v0 += w * (acc[i][2 * c][r]     + locv[2 * c]);
                v1 += w * (acc[i][2 * c + 1][r] + locv[2 * c + 1]);
            }
            yp[(size_t)tl * OUT_F + r16]      = v0;
            yp[(size_t)tl * OUT_F + 16 + r16] = v1;
        }
    }
}

// ---------------------------------------------------------------------------
// Kernel 2 (fallback): verified R-prev fused gemm (fp32 A, reg-cvt-ds_write).
// ---------------------------------------------------------------------------
__global__ __launch_bounds__(256) void gemm_zl_k(const float* __restrict__ A,
                                                 const __hip_bfloat16* __restrict__ BT,
                                                 const float* __restrict__ loc,
                                                 const float* __restrict__ x,
                                                 float* __restrict__ Ypart) {
    __shared__ __align__(16) __hip_bfloat16 As[2][128 * 32];
    __shared__ __align__(16) __hip_bfloat16 Bs[2][128 * 32];
    __shared__ float xs[128][4];

    const int tid  = threadIdx.x;
    const int bm   = blockIdx.x;
    const int bn   = (NBN - 1) - blockIdx.y;
    const int wave = tid >> 6;
    const int lane = tid & 63;
    const int quad = lane >> 4;
    const int r16  = lane & 15;

    const int kblocks = min(KK / 32, 4 * bn + 4);

    {
        const int tl = tid >> 1;
        const int cc = (tid & 1) * 2;
#pragma unroll
        for (int c = cc; c < cc + 2; c++) {
            const int h = 4 * bn - 1 + c;
            float w = 0.0f;
            if (bn == 0 && c == 0)          w = 1.0f;
            else if (h >= 0 && h < IN_F)    w = x[(size_t)(bm * 128 + tl) * IN_F + h];
            xs[tl][c] = w;
        }
    }

    const float*          Ag = A  + (size_t)bm * 128 * KK;
    const __hip_bfloat16* Bg = BT + (size_t)bn * 128 * KK;

    const int c0 = tid, c1 = tid + 256;
    const int ar0 = c0 >> 2, ap0 = (c0 & 3) ^ ((ar0 >> 1) & 3);
    const int ar1 = c1 >> 2, ap1 = (c1 & 3) ^ ((ar1 >> 1) & 3);
    const size_t gofs0 = (size_t)ar0 * KK + ap0 * 8;
    const size_t gofs1 = (size_t)ar1 * KK + ap1 * 8;

    f32x4 acc[2][8];
#pragma unroll
    for (int i = 0; i < 2; i++)
#pragma unroll
        for (int j = 0; j < 8; j++) acc[i][j] = f32x4{0.f, 0.f, 0.f, 0.f};

    int aofs[2], bofs[8];
#pragma unroll
    for (int i = 0; i < 2; i++) {
        const int arow = 32 * wave + 16 * i + r16;
        aofs[i] = arow * 32 + (quad ^ ((arow >> 1) & 3)) * 8;
    }
#pragma unroll
    for (int j = 0; j < 8; j++) {
        const int brow = 16 * j + r16;
        bofs[j] = brow * 32 + (quad ^ ((brow >> 1) & 3)) * 8;
    }

    {
        f32x4 ra0 = *(const f32x4*)(Ag + gofs0);
        f32x4 ra1 = *(const f32x4*)(Ag + gofs0 + 4);
        f32x4 ra2 = *(const f32x4*)(Ag + gofs1);
        f32x4 ra3 = *(const f32x4*)(Ag + gofs1 + 4);
        __builtin_amdgcn_global_load_lds((gas_ptr)(Bg + gofs0), (lds_ptr)(&Bs[0][0] + c0 * 8), 16, 0, 0);
        __builtin_amdgcn_global_load_lds((gas_ptr)(Bg + gofs1), (lds_ptr)(&Bs[0][0] + c1 * 8), 16, 0, 0);
        bf16x8 w0, w1;
#pragma unroll
        for (int q = 0; q < 4; q++) {
            w0[q] = (__bf16)ra0[q]; w0[4 + q] = (__bf16)ra1[q];
            w1[q] = (__bf16)ra2[q]; w1[4 + q] = (__bf16)ra3[q];
        }
        *(bf16x8*)(&As[0][0] + c0 * 8) = w0;
        *(bf16x8*)(&As[0][0] + c1 * 8) = w1;
    }

    for (int kb = 0; kb < kblocks; ++kb) {
        const int cur = kb & 1;
        __syncthreads();

        const bool pf = (kb + 1 < kblocks);
        f32x4 ra0, ra1, ra2, ra3;
        if (pf) {
            const size_t k0 = (size_t)(kb + 1) * 32;
            ra0 = *(const f32x4*)(Ag + k0 + gofs0);
            ra1 = *(const f32x4*)(Ag + k0 + gofs0 + 4);
            ra2 = *(const f32x4*)(Ag + k0 + gofs1);
            ra3 = *(const f32x4*)(Ag + k0 + gofs1 + 4);
            __builtin_amdgcn_global_load_lds((gas_ptr)(Bg + k0 + gofs0), (lds_ptr)(&Bs[cur ^ 1][0] + c0 * 8), 16, 0, 0);
            __builtin_amdgcn_global_load_lds((gas_ptr)(Bg + k0 + gofs1), (lds_ptr)(&Bs[cur ^ 1][0] + c1 * 8), 16, 0, 0);
        }

        bf16x8 af[2], bfr[8];
#pragma unroll
        for (int i = 0; i < 2; i++) af[i]  = *(const bf16x8*)(&As[cur][0] + aofs[i]);
#pragma unroll
        for (int j = 0; j < 8; j++) bfr[j] = *(const bf16x8*)(&Bs[cur][0] + bofs[j]);
#pragma unroll
        for (int i = 0; i < 2; i++)
#pragma unroll
            for (int j = 0; j < 8; j++)
                acc[i][j] = __builtin_amdgcn_mfma_f32_16x16x32_bf16(af[i], bfr[j], acc[i][j], 0, 0, 0);

        if (pf) {
            bf16x8 w0, w1;
#pragma unroll
            for (int q = 0; q < 4; q++) {
                w0[q] = (__bf16)ra0[q]; w0[4 + q] = (__bf16)ra1[q];
                w1[q] = (__bf16)ra2[q]; w1[4 + q] = (__bf16)ra3[q];
            }
            *(bf16x8*)(&As[cur ^ 1][0] + c0 * 8) = w0;
            *(bf16x8*)(&As[cur ^ 1][0] + c1 * 8) = w1;
        }
    }

    float locv[8];
#pragma unroll
    for (int j = 0; j < 8; j++) {
        const int col = bn * 128 + 16 * j + r16;
        locv[j] = (col < NV) ? loc[col] : 0.0f;
    }

    float* yp = Ypart + ((size_t)bn * MM + (size_t)bm * 128) * OUT_F;
#pragma unroll
    for (int i = 0; i < 2; i++) {
#pragma unroll
        for (int r = 0; r < 4; r++) {
            const int tl = 32 * wave + 16 * i + 4 * quad + r;
            float v0 = 0.0f, v1 = 0.0f;
#pragma unroll
            for (int c = 0; c < 4; c++) {
                const float w = xs[tl][c];
                v0 += w * (acc[i][2 * c][r]     + locv[2 * c]);
                v1 += w * (acc[i][2 * c + 1][r] + locv[2 * c + 1]);
            }
            yp[(size_t)tl * OUT_F + r16]      = v0;
            yp[(size_t)tl * OUT_F + 16 + r16] = v1;
        }
    }
}

// ---------------------------------------------------------------------------
// Kernel 3: reduce 17 partials -> y
// ---------------------------------------------------------------------------
__global__ __launch_bounds__(256) void reduce_y_k(const float4* __restrict__ yp,
                                                  float4* __restrict__ y) {
    const size_t i = (size_t)blockIdx.x * 256 + threadIdx.x;   // MM*32/4
    float4 s = yp[i];
#pragma unroll
    for (int b = 1; b < NBN; b++) {
        float4 v = yp[i + (size_t)b * (MM * OUT_F / 4)];
        s.x += v.x; s.y += v.y; s.z += v.z; s.w += v.w;
    }
    y[i] = s;
}

// ---------------------------------------------------------------------------
extern "C" void kernel_launch(void* const* d_in, const int* in_sizes, int n_in,
                              void* d_out, int out_size, void* d_ws, size_t ws_size,
                              hipStream_t stream) {
    const float* x      = (const float*)d_in[0];
    const float* eps    = (const float*)d_in[1];
    const float* loc    = (const float*)d_in[2];
    const float* logvar = (const float*)d_in[3];
    const float* cov    = (const float*)d_in[4];
    float* y = (float*)d_out;

    char* ws = (char*)d_ws;
    const size_t lb_bytes = (size_t)NPAD * KK * 2;            //  9.05 MB
    const size_t eb_bytes = (size_t)MM * KK * 2;              // 68.16 MB
    const size_t yp_bytes = (size_t)NBN * MM * OUT_F * 4;     // 35.65 MB

    if (ws_size >= lb_bytes + eb_bytes + yp_bytes) {
        __hip_bfloat16* LB    = (__hip_bfloat16*)ws;
        __hip_bfloat16* EB    = (__hip_bfloat16*)(ws + lb_bytes);
        float*          Ypart = (float*)(ws + lb_bytes + eb_bytes);

        prep_k<<<CVT_BLKS + L_BLKS, 256, 0, stream>>>(eps, cov, logvar, EB, LB);
        gemm_v2_k<<<dim3(MM / BM, NBN), 256, 0, stream>>>(EB, LB, loc, x, Ypart);
        reduce_y_k<<<(MM * OUT_F / 4) / 256, 256, 0, stream>>>((const float4*)Ypart, (float4*)y);
    } else {
        // fallback: verified previous-session path (needs 44.7 MB ws)
        __hip_bfloat16* LB    = (__hip_bfloat16*)ws;
        float*          Ypart = (float*)(ws + lb_bytes);

        build_L_k<<<(NPAD * KK) / 256, 256, 0, stream>>>(cov, logvar, LB);
        gemm_zl_k<<<dim3(MM / 128, NBN), 256, 0, stream>>>(eps, LB, loc, x, Ypart);
        reduce_y_k<<<(MM * OUT_F / 4) / 256, 256, 0, stream>>>((const float4*)Ypart, (float4*)y);
    }
}

// Round 2
// 315.621 us; speedup vs baseline: 1.0309x; 1.0309x over previous
//
#include <hip/hip_runtime.h>
#include <hip/hip_bf16.h>

// Problem constants (BayesianLinear): IN_F=64, OUT_F=32, N=2080, B*S=16384
#define IN_F  64
#define OUT_F 32
#define NV    2080           // N
#define NPAD  2176           // 17*128
#define MM    16384          // tokens
#define KK    2080           // contraction dim
#define NBN   17             // column tiles
#define BM    256            // row-tile

typedef __attribute__((ext_vector_type(4))) float f32x4;
typedef __bf16 bf16x8 __attribute__((ext_vector_type(8)));

using gas_ptr = const __attribute__((address_space(1))) void*;
using lds_ptr = __attribute__((address_space(3))) void*;

// ---------------------------------------------------------------------------
// Kernel 1: build L (bf16, row-major [NPAD][KK]); rows >= NV are zero.
// ---------------------------------------------------------------------------
__global__ __launch_bounds__(256) void build_L_k(const float* __restrict__ cov,
                                                 const float* __restrict__ logvar,
                                                 __hip_bfloat16* __restrict__ LB) {
    const int idx = blockIdx.x * 256 + threadIdx.x;   // over NPAD*KK
    const int m = idx / KK;
    const int k = idx - m * KK;
    float v = 0.0f;
    if (m < NV) {
        if (k < m)       v = cov[(size_t)(m * (m - 1) / 2) + k];
        else if (k == m) v = expf(0.5f * logvar[m]);
    }
    LB[idx] = __float2bfloat16(v);
}

// ---------------------------------------------------------------------------
// Kernel 2 (v3): BM=256 x 128 tile.
//   A (eps fp32): reg-load -> in-reg cvt -> ds_write_b128, DOUBLE-buffered.
//     Loads for t+1 issue at end of iter t-1 (post-MFMA); cvt+write for t+1
//     happen post-MFMA of iter t -> a full MFMA block covers the latency.
//     (This removes the eps->bf16 pre-pass kernel entirely.)
//   B (L bf16): global_load_lds, TRIPLE-buffered distance-2, counted vmcnt:
//     at the pre-barrier wait, the 2 newest outstanding vm ops are exactly
//     B(t+2) (asm memory clobbers fence reordering), so vmcnt(2) keeps them
//     in flight across the barrier -- never drain in the main loop.
//   4 waves x acc[4][8] (64x128/wave) -> 12 ds_read_b128 per 32 MFMAs.
//   B-frag read per-j inside the MFMA loop (reg pressure + interleave);
//   setprio(1) around the MFMA cluster (T5: phase-split schedule -> waves
//   have role diversity, scheduler can favor MFMA waves).
//   Swizzle (both operands): slot(row,q) holds global part q^((row>>1)&3).
//   Triangular: kblocks=min(65,4bn+4); tail frag-skip jlo=2t-8bn.
//   Epilogue: in-lane x-contraction -> Ypart slab bn (exact R1 epilogue).
// ---------------------------------------------------------------------------
__global__ __launch_bounds__(256, 2) void gemm_v3_k(const float* __restrict__ A,
                                                    const __hip_bfloat16* __restrict__ BT,
                                                    const float* __restrict__ loc,
                                                    const float* __restrict__ x,
                                                    float* __restrict__ Ypart) {
    __shared__ __align__(16) __hip_bfloat16 As[2][BM * 32];    // 32 KB
    __shared__ __align__(16) __hip_bfloat16 Bs[3][128 * 32];   // 24 KB
    __shared__ float xs[BM][4];                                //  4 KB

    const int tid  = threadIdx.x;
    const int bm   = blockIdx.x;             // 0..63
    const int bn   = (NBN - 1) - blockIdx.y; // heaviest (bn=16) first
    const int wave = tid >> 6;
    const int lane = tid & 63;
    const int quad = lane >> 4;
    const int r16  = lane & 15;
    const int kblocks = min(KK / 32, 4 * bn + 4);   // >= 4 always

    // xs: weight for h = 4bn-1+c; bias (1.0) at bn==0,c==0.
    {
        const int row = bm * BM + tid;
#pragma unroll
        for (int c = 0; c < 4; c++) {
            const int h = 4 * bn - 1 + c;
            float w = 0.0f;
            if (bn == 0 && c == 0)       w = 1.0f;
            else if (h >= 0 && h < IN_F) w = x[(size_t)row * IN_F + h];
            xs[tid][c] = w;
        }
    }

    const float*          __restrict__ Ag = A  + (size_t)bm * BM * KK;   // fp32 eps
    const __hip_bfloat16* __restrict__ Bg = BT + (size_t)bn * 128 * KK;  // bf16 L

    // A staging map: 1024 chunks of 8 elems, 4/thread.  chunk c -> LDS slot
    // (row=c>>2, q=c&3) holding global part p=(c&3)^((row>>1)&3).
    size_t agofs[4]; int aldso[4];
#pragma unroll
    for (int u = 0; u < 4; u++) {
        const int c = tid + 256 * u;
        const int r = c >> 2, p = (c & 3) ^ ((r >> 1) & 3);
        agofs[u] = (size_t)r * KK + (size_t)(p * 8);   // fp32 elements
        aldso[u] = c * 8;                              // bf16 elements
    }
    // B staging map: 512 chunks, 2/thread, same swizzle (glds path).
    size_t bgofs[2]; int bldso[2];
#pragma unroll
    for (int u = 0; u < 2; u++) {
        const int c = tid + 256 * u;
        const int r = c >> 2, p = (c & 3) ^ ((r >> 1) & 3);
        bgofs[u] = (size_t)r * KK + (size_t)(p * 8);
        bldso[u] = c * 8;
    }

    // fragment-read LDS offsets (elements), verified swizzle
    int aofs[4], bofs[8];
#pragma unroll
    for (int i = 0; i < 4; i++) {
        const int arow = 64 * wave + 16 * i + r16;
        aofs[i] = arow * 32 + (quad ^ ((arow >> 1) & 3)) * 8;
    }
#pragma unroll
    for (int j = 0; j < 8; j++) {
        const int brow = 16 * j + r16;
        bofs[j] = brow * 32 + (quad ^ ((brow >> 1) & 3)) * 8;
    }

    f32x4 acc[4][8];
#pragma unroll
    for (int i = 0; i < 4; i++)
#pragma unroll
        for (int j = 0; j < 8; j++) acc[i][j] = f32x4{0.f, 0.f, 0.f, 0.f};

    f32x4 ra[8];   // in-flight A tile (fp32), statically indexed only

    auto loadA = [&](int t) __attribute__((always_inline)) {
        const size_t k0 = (size_t)t * 32;
#pragma unroll
        for (int u = 0; u < 4; u++) {
            ra[2 * u]     = *(const f32x4*)(Ag + k0 + agofs[u]);
            ra[2 * u + 1] = *(const f32x4*)(Ag + k0 + agofs[u] + 4);
        }
    };
    auto writeA = [&](int buf) __attribute__((always_inline)) {
#pragma unroll
        for (int u = 0; u < 4; u++) {
            bf16x8 w;
#pragma unroll
            for (int q = 0; q < 4; q++) {
                w[q]     = (__bf16)ra[2 * u][q];
                w[4 + q] = (__bf16)ra[2 * u + 1][q];
            }
            *(bf16x8*)(&As[buf][0] + aldso[u]) = w;
        }
    };
    auto stageB = [&](int t, int buf) __attribute__((always_inline)) {
        const size_t k0 = (size_t)t * 32;
#pragma unroll
        for (int u = 0; u < 2; u++)
            __builtin_amdgcn_global_load_lds((gas_ptr)(Bg + k0 + bgofs[u]),
                                             (lds_ptr)(&Bs[buf][0] + bldso[u]), 16, 0, 0);
    };

    // --- prologue ---  issue order pinned by sched_barriers:
    // A0(8), B0(2), B1(2), [auto-wait for ra], writeA, A1(8), vmcnt(10)->B0 done
    loadA(0);
    __builtin_amdgcn_sched_barrier(0);
    stageB(0, 0);
    stageB(1, 1);
    __builtin_amdgcn_sched_barrier(0);
    writeA(0);                                           // compiler waits A0
    loadA(1);
    __builtin_amdgcn_sched_barrier(0);
    asm volatile("s_waitcnt vmcnt(10)" ::: "memory");    // drain B0; keep B1+A1
    asm volatile("s_waitcnt lgkmcnt(0)" ::: "memory");   // A ds_writes + xs
    __builtin_amdgcn_s_barrier();
    __builtin_amdgcn_sched_barrier(0);

    // invariant at entry of iter t: As[t&1], Bs[t%3] ready for all waves;
    // ra holds A(t+1) (if any); outstanding vm: B(t+1)[2], A(t+1)[8] (if any).
    auto iter = [&](int t, int jlo) __attribute__((always_inline)) {
        const bool pfA = (t + 1 < kblocks);
        const bool pfB = (t + 2 < kblocks);
        if (pfB) stageB(t + 2, (t + 2) % 3);     // issued pre-MFMA: full cover
        const __hip_bfloat16* as = &As[t & 1][0];
        const __hip_bfloat16* bs = &Bs[t % 3][0];
        bf16x8 af[4];
#pragma unroll
        for (int i = 0; i < 4; i++) af[i] = *(const bf16x8*)(as + aofs[i]);
        __builtin_amdgcn_s_setprio(1);
#pragma unroll
        for (int j = 0; j < 8; j++) {
            if (j >= jlo) {
                const bf16x8 bf = *(const bf16x8*)(bs + bofs[j]);
#pragma unroll
                for (int i = 0; i < 4; i++)
                    acc[i][j] = __builtin_amdgcn_mfma_f32_16x16x32_bf16(af[i], bf, acc[i][j], 0, 0, 0);
            }
        }
        __builtin_amdgcn_s_setprio(0);
        if (pfA) {
            // land A(t+1)+B(t+1); keep B(t+2) (the 2 newest) in flight.
            if (pfB) { asm volatile("s_waitcnt vmcnt(2)" ::: "memory"); }
            else     { asm volatile("s_waitcnt vmcnt(0)" ::: "memory"); }
            writeA((t + 1) & 1);
            if (pfB) loadA(t + 2);
            asm volatile("s_waitcnt lgkmcnt(0)" ::: "memory");  // ds_writes visible
            __builtin_amdgcn_s_barrier();
            __builtin_amdgcn_sched_barrier(0);
        }
    };

    const int t_full = min(kblocks, 4 * bn + 1);   // jlo==0 region
    int t = 0;
    for (; t < t_full; ++t) iter(t, 0);
    for (; t < kblocks; ++t) iter(t, 2 * t - 8 * bn);   // jlo in {2,4,6}

    // in-lane epilogue.  C/D layout (m89): col=lane&15 (per 16-tile), row=quad*4+reg
    float locv[8];
#pragma unroll
    for (int j = 0; j < 8; j++) {
        const int col = bn * 128 + 16 * j + r16;
        locv[j] = (col < NV) ? loc[col] : 0.0f;
    }

    float* yp = Ypart + ((size_t)bn * MM + (size_t)bm * BM) * OUT_F;
#pragma unroll
    for (int i = 0; i < 4; i++) {
#pragma unroll
        for (int r = 0; r < 4; r++) {
            const int tl = 64 * wave + 16 * i + 4 * quad + r;
            float v0 = 0.0f, v1 = 0.0f;
#pragma unroll
            for (int c = 0; c < 4; c++) {
                const float w = xs[tl][c];
                v0 += w * (acc[i][2 * c][r]     + locv[2 * c]);
                v1 += w * (acc[i][2 * c + 1][r] + locv[2 * c + 1]);
            }
            yp[(size_t)tl * OUT_F + r16]      = v0;
            yp[(size_t)tl * OUT_F + 16 + r16] = v1;
        }
    }
}

// ---------------------------------------------------------------------------
// Kernel 3: reduce 17 partials -> y
// ---------------------------------------------------------------------------
__global__ __launch_bounds__(256) void reduce_y_k(const float4* __restrict__ yp,
                                                  float4* __restrict__ y) {
    const size_t i = (size_t)blockIdx.x * 256 + threadIdx.x;   // MM*32/4
    float4 s = yp[i];
#pragma unroll
    for (int b = 1; b < NBN; b++) {
        float4 v = yp[i + (size_t)b * (MM * OUT_F / 4)];
        s.x += v.x; s.y += v.y; s.z += v.z; s.w += v.w;
    }
    y[i] = s;
}

// ---------------------------------------------------------------------------
extern "C" void kernel_launch(void* const* d_in, const int* in_sizes, int n_in,
                              void* d_out, int out_size, void* d_ws, size_t ws_size,
                              hipStream_t stream) {
    const float* x      = (const float*)d_in[0];
    const float* eps    = (const float*)d_in[1];
    const float* loc    = (const float*)d_in[2];
    const float* logvar = (const float*)d_in[3];
    const float* cov    = (const float*)d_in[4];
    float* y = (float*)d_out;

    char* ws = (char*)d_ws;
    const size_t lb_bytes = (size_t)NPAD * KK * 2;            //  9.05 MB
    __hip_bfloat16* LB    = (__hip_bfloat16*)ws;
    float*          Ypart = (float*)(ws + lb_bytes);          // 35.65 MB

    build_L_k<<<(NPAD * KK) / 256, 256, 0, stream>>>(cov, logvar, LB);
    gemm_v3_k<<<dim3(MM / BM, NBN), 256, 0, stream>>>(eps, LB, loc, x, Ypart);
    reduce_y_k<<<(MM * OUT_F / 4) / 256, 256, 0, stream>>>((const float4*)Ypart, (float4*)y);
}